// Round 8
// baseline (3185.357 us; speedup 1.0000x reference)
//
#include <hip/hip_runtime.h>
#include <cstdint>
#include <cstddef>

// ---------------------------------------------------------------------------
// GCN 2-layer: h = relu(Agg(x@W1)); out = relu(Agg(h@W3))
// Agg = D^-1/2 (A+I) D^-1/2. Identity used: out[d] = relu(dinv[d]*(hs[d]+Σ hs[s]))
// where hs = (A@W)·dinv[row]  (scaling fused into GEMM epilogue).
// Edges compressed to one word: (src<<6)|dstLocal, bucketed by dst>>6.
// Aggregation: block-per-bucket, fp32 LDS accumulator + LDS atomics
// (lane->column mapping => bank = lane%32, conflict-free).
// agg256 gather is pinned at ~3.4 TB/s beyond-L2 (random-gather fabric wall).
// ---------------------------------------------------------------------------

#define NPART 128   // blocks for histogram/scatter phases

__device__ __forceinline__ float bf2f(unsigned short u) {
    union { unsigned int i; float f; } c; c.i = ((unsigned int)u) << 16; return c.f;
}
__device__ __forceinline__ unsigned short f2bf(float f) {
    union { float f; unsigned int i; } c; c.f = f;
    unsigned int r = c.i + 0x7fffu + ((c.i >> 16) & 1u);   // round-nearest-even
    return (unsigned short)(r >> 16);
}

// both weight transposes in one launch: W[K][N] fp32 -> Wt[N][K] bf16
__global__ __launch_bounds__(256) void wcvt2_kernel(const float* __restrict__ W1,
                                                    const float* __restrict__ W3,
                                                    unsigned short* __restrict__ W1t,
                                                    unsigned short* __restrict__ W3t) {
    int idx = blockIdx.x * 256 + threadIdx.x;
    if (idx < 256 * 256) {
        int nn = idx >> 8, kk = idx & 255;          // N=256, K=256
        W1t[idx] = f2bf(W1[kk * 256 + nn]);
    } else if (idx < 256 * 256 + 64 * 256) {
        int j = idx - 256 * 256;
        int nn = j >> 8, kk = j & 255;              // N=64, K=256
        W3t[j] = f2bf(W3[kk * 64 + nn]);
    }
}

// ---- graph build: bucket partition (64 nodes/bucket) ----------------------

__global__ __launch_bounds__(256) void part_hist(const int* __restrict__ dst, int E, int NB,
                                                 int* __restrict__ blockhist) {
    __shared__ int lh[1024];
    for (int t = threadIdx.x; t < NB; t += 256) lh[t] = 0;
    __syncthreads();
    const int per = (E + NPART - 1) / NPART;
    const int beg = blockIdx.x * per;
    const int end = min(E, beg + per);
    for (int i = beg + threadIdx.x; i < end; i += 256)
        atomicAdd(&lh[dst[i] >> 6], 1);
    __syncthreads();
    for (int t = threadIdx.x; t < NB; t += 256)
        blockhist[blockIdx.x * NB + t] = lh[t];
}

__global__ __launch_bounds__(1024) void part_scan(const int* __restrict__ blockhist,
                                                  int* __restrict__ bofs,
                                                  int* __restrict__ bbase, int NB) {
    __shared__ int wsum[16];
    const int t = threadIdx.x;
    const int lane = t & 63;
    int tot = 0;
    if (t < NB) {
        #pragma unroll 4
        for (int k = 0; k < NPART; ++k) tot += blockhist[k * NB + t];
    }
    int x = tot;
    #pragma unroll
    for (int off = 1; off < 64; off <<= 1) {
        int q = __shfl_up(x, off);
        if (lane >= off) x += q;
    }
    if (lane == 63) wsum[t >> 6] = x;
    __syncthreads();
    if (t < 64) {
        int y = (t < 16) ? wsum[t] : 0;
        #pragma unroll
        for (int off = 1; off < 16; off <<= 1) {
            int q = __shfl_up(y, off);
            if (lane >= off) y += q;
        }
        if (t < 16) wsum[t] = y;
    }
    __syncthreads();
    int excl = ((t >> 6) ? wsum[(t >> 6) - 1] : 0) + x - tot;
    if (t < NB) {
        bofs[t] = excl;
        if (t == NB - 1) bofs[NB] = excl + tot;
        int run = excl;
        for (int k = 0; k < NPART; ++k) {
            int c = blockhist[k * NB + t];
            bbase[k * NB + t] = run;
            run += c;
        }
    }
}

// scatter compressed edge words (src<<6 | dstLocal) into bucket regions
__global__ __launch_bounds__(256) void part_scatter(const int* __restrict__ src,
                                                    const int* __restrict__ dst,
                                                    const int* __restrict__ bbase,
                                                    unsigned int* __restrict__ words,
                                                    int E, int NB) {
    __shared__ int lbase[1024];
    for (int t = threadIdx.x; t < NB; t += 256) lbase[t] = bbase[blockIdx.x * NB + t];
    __syncthreads();
    const int per = (E + NPART - 1) / NPART;
    const int beg = blockIdx.x * per;
    const int end = min(E, beg + per);
    for (int i = beg + threadIdx.x; i < end; i += 256) {
        int d = dst[i];
        int off = atomicAdd(&lbase[d >> 6], 1);
        words[off] = ((unsigned)src[i] << 6) | (unsigned)(d & 63);
    }
}

// per-bucket degrees -> dinv
__global__ __launch_bounds__(256) void bucket_deg(const unsigned int* __restrict__ words,
                                                  const int* __restrict__ bofs,
                                                  float* __restrict__ dinv, int n) {
    const int b = blockIdx.x;
    __shared__ int ldeg[64];
    if (threadIdx.x < 64) ldeg[threadIdx.x] = 0;
    __syncthreads();
    const int beg = bofs[b], end = bofs[b + 1];
    for (int i = beg + threadIdx.x; i < end; i += 256)
        atomicAdd(&ldeg[words[i] & 63u], 1);
    __syncthreads();
    if (threadIdx.x < 64) {
        int node = (b << 6) + threadIdx.x;
        if (node < n) dinv[node] = rsqrtf((float)(ldeg[threadIdx.x] + 1));
    }
}

// ---- bf16 MFMA GEMM: C[M,N] = (A[M,K] @ Bt[N,K]^T) * dinv[row] ------------
// BM=128, BK=64, 256 threads (4 waves). AF32: fp32 A with fused bf16 cvt.
template<int BN, int WM, int WN, bool AF32>
__global__ __launch_bounds__(256) void mfma_gemm(const void* __restrict__ Av,
                                                 const unsigned short* __restrict__ Bt,
                                                 const float* __restrict__ dinvp,
                                                 unsigned short* __restrict__ C,
                                                 int M, int N, int K) {
    constexpr int BM = 128, BK = 64;
    constexpr int KP = 72;
    constexpr int WTM = BM / WM;
    constexpr int WTN = BN / WN;
    constexpr int MF = WTM / 16;
    constexpr int NF = WTN / 16;
    __shared__ unsigned short As[BM][KP];
    __shared__ unsigned short Bs[BN][KP];
    const int tid = threadIdx.x;
    const int wid = tid >> 6;
    const int lane = tid & 63;
    const int wr = wid / WN;
    const int wc = wid % WN;
    const int bm = blockIdx.y * BM;
    const int bn = blockIdx.x * BN;
    const int l15 = lane & 15;
    const int lg = lane >> 4;

    using bf16x8 = __attribute__((ext_vector_type(8))) short;
    using f32x4  = __attribute__((ext_vector_type(4))) float;
    f32x4 acc[MF][NF] = {};

    for (int k0 = 0; k0 < K; k0 += BK) {
        #pragma unroll
        for (int it = 0; it < (BM * BK / 8) / 256; ++it) {
            int v = tid + 256 * it;
            int row = v >> 3;
            int oct = v & 7;
            uint4 val = make_uint4(0, 0, 0, 0);
            int gr = bm + row;
            if (gr < M) {
                if (AF32) {
                    const float* A32 = (const float*)Av;
                    float4 f0 = *(const float4*)(A32 + (size_t)gr * K + k0 + oct * 8);
                    float4 f1 = *(const float4*)(A32 + (size_t)gr * K + k0 + oct * 8 + 4);
                    union { unsigned short u[8]; uint4 v4; } pk;
                    pk.u[0] = f2bf(f0.x); pk.u[1] = f2bf(f0.y);
                    pk.u[2] = f2bf(f0.z); pk.u[3] = f2bf(f0.w);
                    pk.u[4] = f2bf(f1.x); pk.u[5] = f2bf(f1.y);
                    pk.u[6] = f2bf(f1.z); pk.u[7] = f2bf(f1.w);
                    val = pk.v4;
                } else {
                    const unsigned short* Ab = (const unsigned short*)Av;
                    val = *(const uint4*)(Ab + (size_t)gr * K + k0 + oct * 8);
                }
            }
            *(uint4*)(&As[row][oct * 8]) = val;
        }
        #pragma unroll
        for (int it = 0; it < (BN * BK / 8) / 256; ++it) {
            int v = tid + 256 * it;
            int row = v >> 3;
            int oct = v & 7;
            uint4 val = *(const uint4*)(Bt + (size_t)(bn + row) * K + k0 + oct * 8);
            *(uint4*)(&Bs[row][oct * 8]) = val;
        }
        __syncthreads();
        #pragma unroll
        for (int kk = 0; kk < 2; ++kk) {
            bf16x8 af[MF], bfr[NF];
            #pragma unroll
            for (int m = 0; m < MF; ++m)
                af[m] = *(const bf16x8*)(&As[wr * WTM + m * 16 + l15][kk * 32 + lg * 8]);
            #pragma unroll
            for (int nf = 0; nf < NF; ++nf)
                bfr[nf] = *(const bf16x8*)(&Bs[wc * WTN + nf * 16 + l15][kk * 32 + lg * 8]);
            #pragma unroll
            for (int m = 0; m < MF; ++m)
                #pragma unroll
                for (int nf = 0; nf < NF; ++nf)
                    acc[m][nf] = __builtin_amdgcn_mfma_f32_16x16x32_bf16(
                        af[m], bfr[nf], acc[m][nf], 0, 0, 0);
        }
        __syncthreads();
    }
    // C/D layout: col=lane&15, row=(lane>>4)*4+reg  [HW-verified]
    #pragma unroll
    for (int m = 0; m < MF; ++m) {
        #pragma unroll
        for (int j = 0; j < 4; ++j) {
            int row = bm + wr * WTM + m * 16 + lg * 4 + j;
            if (row < M) {
                float s = dinvp[row];
                #pragma unroll
                for (int nf = 0; nf < NF; ++nf) {
                    int col = bn + wc * WTN + nf * 16 + l15;
                    C[(size_t)row * N + col] = f2bf(acc[m][nf][j] * s);
                }
            }
        }
    }
}

// ---- bucket-fused aggregation ----------------------------------------------
// F=256: grid (NB, 2); col-group = 128 cols. LDS acc 64x128 f32 (32KB).
// out[d] = relu(dinv[d] * (hs[d] + sum_{s in N(d)} hs[s]))  (bf16 out)
__global__ __launch_bounds__(256) void agg256_bucket(
        const unsigned short* __restrict__ hs, const unsigned int* __restrict__ words,
        const int* __restrict__ bofs, const float* __restrict__ dinv,
        unsigned short* __restrict__ out, int n) {
    const int b = blockIdx.x;
    const int colbase = blockIdx.y * 128;
    const int node0 = b << 6;
    __shared__ float acc[64][128];
    __shared__ unsigned int ew[256];
    const int tid = threadIdx.x;
    const int wid = tid >> 6;
    const int lane = tid & 63;

    // init with self-loop rows (hs already dinv[row]-scaled)
    for (int idx = tid; idx < 64 * 128; idx += 256) {
        int r = idx >> 7, c = idx & 127;
        int node = node0 + r;
        acc[r][c] = (node < n) ? bf2f(hs[(size_t)node * 256 + colbase + c]) : 0.f;
    }
    __syncthreads();

    const int beg = bofs[b], end = bofs[b + 1];
    for (int k0 = beg; k0 < end; k0 += 256) {
        int cnt = min(256, end - k0);
        if (tid < cnt) ew[tid] = words[k0 + tid];
        __syncthreads();
        #pragma unroll 4
        for (int e = wid; e < cnt; e += 4) {
            unsigned int w = ew[e];
            const unsigned short* row = hs + (size_t)(w >> 6) * 256 + colbase;
            int dl = w & 63;
            float v0 = bf2f(row[lane]);
            float v1 = bf2f(row[64 + lane]);
            atomicAdd(&acc[dl][lane], v0);        // bank = lane%32: conflict-free
            atomicAdd(&acc[dl][64 + lane], v1);
        }
        __syncthreads();
    }

    for (int idx = tid; idx < 64 * 128; idx += 256) {
        int r = idx >> 7, c = idx & 127;
        int node = node0 + r;
        if (node < n)
            out[(size_t)node * 256 + colbase + c] = f2bf(fmaxf(dinv[node] * acc[r][c], 0.f));
    }
}

// F=64: grid NB. LDS acc 64x64 f32 (16KB). fp32 out.
__global__ __launch_bounds__(256) void agg64_bucket(
        const unsigned short* __restrict__ hs, const unsigned int* __restrict__ words,
        const int* __restrict__ bofs, const float* __restrict__ dinv,
        float* __restrict__ out, int n) {
    const int b = blockIdx.x;
    const int node0 = b << 6;
    __shared__ float acc[64][64];
    __shared__ unsigned int ew[256];
    const int tid = threadIdx.x;
    const int wid = tid >> 6;
    const int lane = tid & 63;

    for (int idx = tid; idx < 64 * 64; idx += 256) {
        int r = idx >> 6, c = idx & 63;
        int node = node0 + r;
        acc[r][c] = (node < n) ? bf2f(hs[(size_t)node * 64 + c]) : 0.f;
    }
    __syncthreads();

    const int beg = bofs[b], end = bofs[b + 1];
    for (int k0 = beg; k0 < end; k0 += 256) {
        int cnt = min(256, end - k0);
        if (tid < cnt) ew[tid] = words[k0 + tid];
        __syncthreads();
        #pragma unroll 4
        for (int e = wid; e < cnt; e += 4) {
            unsigned int w = ew[e];
            float v = bf2f(hs[(size_t)(w >> 6) * 64 + lane]);
            atomicAdd(&acc[w & 63][lane], v);     // bank = lane%32: conflict-free
        }
        __syncthreads();
    }

    for (int idx = tid; idx < 64 * 64; idx += 256) {
        int r = idx >> 6, c = idx & 63;
        int node = node0 + r;
        if (node < n)
            out[(size_t)node * 64 + c] = fmaxf(dinv[node] * acc[r][c], 0.f);
    }
}

// ---------------------------------------------------------------------------

static inline size_t align256(size_t v) { return (v + 255) & ~(size_t)255; }

extern "C" void kernel_launch(void* const* d_in, const int* in_sizes, int n_in,
                              void* d_out, int out_size, void* d_ws, size_t ws_size,
                              hipStream_t stream) {
    const float* x  = (const float*)d_in[0];
    const int*   ei = (const int*)d_in[1];
    const float* W1 = (const float*)d_in[2];
    const float* W3 = (const float*)d_in[3];

    const int n = in_sizes[0] / 256;     // 50000
    const int E = in_sizes[1] / 2;       // 1600000
    const int NB = (n + 63) >> 6;        // 782 buckets
    const int* src = ei;
    const int* dst = ei + E;

    char* w = (char*)d_ws;
    auto alloc = [&](size_t bytes) { char* p = w; w += align256(bytes); return p; };
    unsigned short* hs1  = (unsigned short*)alloc((size_t)n * 256 * 2);
    unsigned short* a1   = (unsigned short*)alloc((size_t)n * 256 * 2);
    unsigned short* hs2  = (unsigned short*)alloc((size_t)n * 64 * 2);
    unsigned short* W1t  = (unsigned short*)alloc(256 * 256 * 2);
    unsigned short* W3t  = (unsigned short*)alloc(64 * 256 * 2);
    float* dinv          = (float*)alloc((size_t)n * 4);
    unsigned int* words  = (unsigned int*)alloc((size_t)E * 4);
    int*   blockhist     = (int*)alloc((size_t)NPART * NB * 4);
    int*   bbase         = (int*)alloc((size_t)NPART * NB * 4);
    int*   bofs          = (int*)alloc((size_t)(NB + 1) * 4);
    float* out           = (float*)d_out;

    wcvt2_kernel<<<(256 * 256 + 64 * 256 + 255) / 256, 256, 0, stream>>>(W1, W3, W1t, W3t);

    part_hist<<<NPART, 256, 0, stream>>>(dst, E, NB, blockhist);
    part_scan<<<1, 1024, 0, stream>>>(blockhist, bofs, bbase, NB);
    part_scatter<<<NPART, 256, 0, stream>>>(src, dst, bbase, words, E, NB);
    bucket_deg<<<NB, 256, 0, stream>>>(words, bofs, dinv, n);

    // layer 1: hs1 = bf16((x @ W1) * dinv); a1 = relu-agg (bf16)
    {
        dim3 grid(1, (n + 127) / 128);
        mfma_gemm<256, 2, 2, true><<<grid, 256, 0, stream>>>(x, W1t, dinv, hs1, n, 256, 256);
        dim3 agrid(NB, 2);
        agg256_bucket<<<agrid, 256, 0, stream>>>(hs1, words, bofs, dinv, a1, n);
    }
    // layer 2: hs2 = bf16((a1 @ W3) * dinv); out = relu-agg (fp32)
    {
        dim3 grid(1, (n + 127) / 128);
        mfma_gemm<64, 4, 1, false><<<grid, 256, 0, stream>>>(a1, W3t, dinv, hs2, n, 64, 256);
        agg64_bucket<<<NB, 256, 0, stream>>>(hs2, words, bofs, dinv, out, n);
    }
}

// Round 9
// 309.098 us; speedup vs baseline: 10.3053x; 10.3053x over previous
//
#include <hip/hip_runtime.h>
#include <cstdint>
#include <cstddef>

// ---------------------------------------------------------------------------
// GCN 2-layer: h = relu(Agg(x@W1)); out = relu(Agg(h@W3))
// Agg = D^-1/2 (A+I) D^-1/2. Identity: out[d] = relu(dinv[d]*(hs[d]+Σ hs[s]))
// with hs = (A@W)·dinv[row] fused into the GEMM epilogue.
// GEMMs: bf16 MFMA 16x16x32, fp32 acc. Aggregation: block-per-node pull,
// LDS-staged edge offsets, 512B wave-gathers, unroll 8 (R6 structure —
// proven pinned at ~3.4 TB/s beyond-L2 random-gather fabric wall).
// Edges: 4B words (src<<6 | dstLocal), bucketed by dst>>6 (64 nodes/bucket).
// ---------------------------------------------------------------------------

#define NPART 128   // blocks for histogram/scatter phases

__device__ __forceinline__ float bf2f(unsigned short u) {
    union { unsigned int i; float f; } c; c.i = ((unsigned int)u) << 16; return c.f;
}
__device__ __forceinline__ unsigned short f2bf(float f) {
    union { float f; unsigned int i; } c; c.f = f;
    unsigned int r = c.i + 0x7fffu + ((c.i >> 16) & 1u);   // round-nearest-even
    return (unsigned short)(r >> 16);
}

// both weight transposes in one launch: W[K][N] fp32 -> Wt[N][K] bf16
__global__ __launch_bounds__(256) void wcvt2_kernel(const float* __restrict__ W1,
                                                    const float* __restrict__ W3,
                                                    unsigned short* __restrict__ W1t,
                                                    unsigned short* __restrict__ W3t) {
    int idx = blockIdx.x * 256 + threadIdx.x;
    if (idx < 256 * 256) {
        int nn = idx >> 8, kk = idx & 255;          // N=256, K=256
        W1t[idx] = f2bf(W1[kk * 256 + nn]);
    } else if (idx < 256 * 256 + 64 * 256) {
        int j = idx - 256 * 256;
        int nn = j >> 8, kk = j & 255;              // N=64, K=256
        W3t[j] = f2bf(W3[kk * 64 + nn]);
    }
}

// ---- graph build: bucket partition (64 nodes/bucket) ----------------------

__global__ __launch_bounds__(256) void part_hist(const int* __restrict__ dst, int E, int NB,
                                                 int* __restrict__ blockhist) {
    __shared__ int lh[1024];
    for (int t = threadIdx.x; t < NB; t += 256) lh[t] = 0;
    __syncthreads();
    const int per = (E + NPART - 1) / NPART;
    const int beg = blockIdx.x * per;
    const int end = min(E, beg + per);
    for (int i = beg + threadIdx.x; i < end; i += 256)
        atomicAdd(&lh[dst[i] >> 6], 1);
    __syncthreads();
    for (int t = threadIdx.x; t < NB; t += 256)
        blockhist[blockIdx.x * NB + t] = lh[t];
}

__global__ __launch_bounds__(1024) void part_scan(const int* __restrict__ blockhist,
                                                  int* __restrict__ bofs,
                                                  int* __restrict__ bbase, int NB) {
    __shared__ int wsum[16];
    const int t = threadIdx.x;
    const int lane = t & 63;
    int tot = 0;
    if (t < NB) {
        #pragma unroll 4
        for (int k = 0; k < NPART; ++k) tot += blockhist[k * NB + t];
    }
    int x = tot;
    #pragma unroll
    for (int off = 1; off < 64; off <<= 1) {
        int q = __shfl_up(x, off);
        if (lane >= off) x += q;
    }
    if (lane == 63) wsum[t >> 6] = x;
    __syncthreads();
    if (t < 64) {
        int y = (t < 16) ? wsum[t] : 0;
        #pragma unroll
        for (int off = 1; off < 16; off <<= 1) {
            int q = __shfl_up(y, off);
            if (lane >= off) y += q;
        }
        if (t < 16) wsum[t] = y;
    }
    __syncthreads();
    int excl = ((t >> 6) ? wsum[(t >> 6) - 1] : 0) + x - tot;
    if (t < NB) {
        bofs[t] = excl;
        if (t == NB - 1) bofs[NB] = excl + tot;
        int run = excl;
        for (int k = 0; k < NPART; ++k) {
            int c = blockhist[k * NB + t];
            bbase[k * NB + t] = run;
            run += c;
        }
    }
}

// scatter compressed edge words (src<<6 | dstLocal) into bucket regions
__global__ __launch_bounds__(256) void part_scatter(const int* __restrict__ src,
                                                    const int* __restrict__ dst,
                                                    const int* __restrict__ bbase,
                                                    unsigned int* __restrict__ words,
                                                    int E, int NB) {
    __shared__ int lbase[1024];
    for (int t = threadIdx.x; t < NB; t += 256) lbase[t] = bbase[blockIdx.x * NB + t];
    __syncthreads();
    const int per = (E + NPART - 1) / NPART;
    const int beg = blockIdx.x * per;
    const int end = min(E, beg + per);
    for (int i = beg + threadIdx.x; i < end; i += 256) {
        int d = dst[i];
        int off = atomicAdd(&lbase[d >> 6], 1);
        words[off] = ((unsigned)src[i] << 6) | (unsigned)(d & 63);
    }
}

// one block per bucket: local degrees -> rowptr, dinv, csr (src-only, sorted by dst)
__global__ __launch_bounds__(256) void bucket_build(const unsigned int* __restrict__ words,
                                                    const int* __restrict__ bofs,
                                                    int* __restrict__ rowptr,
                                                    float* __restrict__ dinv,
                                                    int* __restrict__ csr, int n) {
    const int b = blockIdx.x;
    const int node0 = b << 6;
    __shared__ int ldeg[64], lcur[64];
    if (threadIdx.x < 64) ldeg[threadIdx.x] = 0;
    __syncthreads();
    const int beg = bofs[b], end = bofs[b + 1];
    for (int i = beg + threadIdx.x; i < end; i += 256)
        atomicAdd(&ldeg[words[i] & 63u], 1);
    __syncthreads();
    if (threadIdx.x < 64) {
        const int lane = threadIdx.x;
        int v = ldeg[lane];
        int x = v;
        #pragma unroll
        for (int off = 1; off < 64; off <<= 1) {
            int q = __shfl_up(x, off);
            if (lane >= off) x += q;
        }
        int excl = x - v;
        int node = node0 + lane;
        if (node < n) {
            rowptr[node] = beg + excl;
            dinv[node] = rsqrtf((float)(v + 1));
        }
        lcur[lane] = beg + excl;
        if (b == (int)gridDim.x - 1 && lane == 0) rowptr[n] = end;
    }
    __syncthreads();
    for (int i = beg + threadIdx.x; i < end; i += 256) {
        unsigned int w = words[i];
        int pos = atomicAdd(&lcur[w & 63u], 1);
        csr[pos] = (int)(w >> 6);
    }
}

// ---- bf16 MFMA GEMM: C[M,N] = (A[M,K] @ Bt[N,K]^T) * dinv[row] ------------
// BM=128, BK=64, 256 threads (4 waves). AF32: fp32 A with fused bf16 cvt.
template<int BN, int WM, int WN, bool AF32>
__global__ __launch_bounds__(256) void mfma_gemm(const void* __restrict__ Av,
                                                 const unsigned short* __restrict__ Bt,
                                                 const float* __restrict__ dinvp,
                                                 unsigned short* __restrict__ C,
                                                 int M, int N, int K) {
    constexpr int BM = 128, BK = 64;
    constexpr int KP = 72;
    constexpr int WTM = BM / WM;
    constexpr int WTN = BN / WN;
    constexpr int MF = WTM / 16;
    constexpr int NF = WTN / 16;
    __shared__ unsigned short As[BM][KP];
    __shared__ unsigned short Bs[BN][KP];
    const int tid = threadIdx.x;
    const int wid = tid >> 6;
    const int lane = tid & 63;
    const int wr = wid / WN;
    const int wc = wid % WN;
    const int bm = blockIdx.y * BM;
    const int bn = blockIdx.x * BN;
    const int l15 = lane & 15;
    const int lg = lane >> 4;

    using bf16x8 = __attribute__((ext_vector_type(8))) short;
    using f32x4  = __attribute__((ext_vector_type(4))) float;
    f32x4 acc[MF][NF] = {};

    for (int k0 = 0; k0 < K; k0 += BK) {
        #pragma unroll
        for (int it = 0; it < (BM * BK / 8) / 256; ++it) {
            int v = tid + 256 * it;
            int row = v >> 3;
            int oct = v & 7;
            uint4 val = make_uint4(0, 0, 0, 0);
            int gr = bm + row;
            if (gr < M) {
                if (AF32) {
                    const float* A32 = (const float*)Av;
                    float4 f0 = *(const float4*)(A32 + (size_t)gr * K + k0 + oct * 8);
                    float4 f1 = *(const float4*)(A32 + (size_t)gr * K + k0 + oct * 8 + 4);
                    union { unsigned short u[8]; uint4 v4; } pk;
                    pk.u[0] = f2bf(f0.x); pk.u[1] = f2bf(f0.y);
                    pk.u[2] = f2bf(f0.z); pk.u[3] = f2bf(f0.w);
                    pk.u[4] = f2bf(f1.x); pk.u[5] = f2bf(f1.y);
                    pk.u[6] = f2bf(f1.z); pk.u[7] = f2bf(f1.w);
                    val = pk.v4;
                } else {
                    const unsigned short* Ab = (const unsigned short*)Av;
                    val = *(const uint4*)(Ab + (size_t)gr * K + k0 + oct * 8);
                }
            }
            *(uint4*)(&As[row][oct * 8]) = val;
        }
        #pragma unroll
        for (int it = 0; it < (BN * BK / 8) / 256; ++it) {
            int v = tid + 256 * it;
            int row = v >> 3;
            int oct = v & 7;
            uint4 val = *(const uint4*)(Bt + (size_t)(bn + row) * K + k0 + oct * 8);
            *(uint4*)(&Bs[row][oct * 8]) = val;
        }
        __syncthreads();
        #pragma unroll
        for (int kk = 0; kk < 2; ++kk) {
            bf16x8 af[MF], bfr[NF];
            #pragma unroll
            for (int m = 0; m < MF; ++m)
                af[m] = *(const bf16x8*)(&As[wr * WTM + m * 16 + l15][kk * 32 + lg * 8]);
            #pragma unroll
            for (int nf = 0; nf < NF; ++nf)
                bfr[nf] = *(const bf16x8*)(&Bs[wc * WTN + nf * 16 + l15][kk * 32 + lg * 8]);
            #pragma unroll
            for (int m = 0; m < MF; ++m)
                #pragma unroll
                for (int nf = 0; nf < NF; ++nf)
                    acc[m][nf] = __builtin_amdgcn_mfma_f32_16x16x32_bf16(
                        af[m], bfr[nf], acc[m][nf], 0, 0, 0);
        }
        __syncthreads();
    }
    // C/D layout: col=lane&15, row=(lane>>4)*4+reg  [HW-verified]
    #pragma unroll
    for (int m = 0; m < MF; ++m) {
        #pragma unroll
        for (int j = 0; j < 4; ++j) {
            int row = bm + wr * WTM + m * 16 + lg * 4 + j;
            if (row < M) {
                float s = dinvp[row];
                #pragma unroll
                for (int nf = 0; nf < NF; ++nf) {
                    int col = bn + wc * WTN + nf * 16 + l15;
                    C[(size_t)row * N + col] = f2bf(acc[m][nf][j] * s);
                }
            }
        }
    }
}

// ---- aggregation: block-per-node pull, LDS-staged offsets -----------------
// F=256, hs bf16 in / bf16 out. out[d] = relu(dinv[d]*(hs[d] + Σ hs[s])).
__global__ __launch_bounds__(256) void aggregate256_kernel(
        const unsigned short* __restrict__ hs, const int* __restrict__ rowptr,
        const int* __restrict__ csr, const float* __restrict__ dinv,
        unsigned short* __restrict__ out, int n) {
    const int d = blockIdx.x;
    const int tid = threadIdx.x;
    const int wid = tid >> 6;
    const int lane = tid & 63;
    const int beg = rowptr[d];
    const int end = rowptr[d + 1];

    float acc0 = 0.f, acc1 = 0.f, acc2 = 0.f, acc3 = 0.f;
    if (wid == 0) {   // self-loop: dinv[d]*hs[d] handled by final scale
        ushort4 t = *(const ushort4*)(hs + (size_t)d * 256 + lane * 4);
        acc0 = bf2f(t.x); acc1 = bf2f(t.y); acc2 = bf2f(t.z); acc3 = bf2f(t.w);
    }

    __shared__ unsigned int soff[256];
    const char* hb = (const char*)hs;
    for (int k0 = beg; k0 < end; k0 += 256) {
        int cnt = min(256, end - k0);
        if (tid < cnt) soff[tid] = (unsigned)csr[k0 + tid] * 512u;
        __syncthreads();
        #pragma unroll 8
        for (int e = wid; e < cnt; e += 4) {
            ushort4 t = *(const ushort4*)(hb + soff[e] + lane * 8);
            acc0 += bf2f(t.x); acc1 += bf2f(t.y);
            acc2 += bf2f(t.z); acc3 += bf2f(t.w);
        }
        __syncthreads();
    }

    __shared__ float part[3][256];
    if (wid > 0) {
        part[wid - 1][lane * 4 + 0] = acc0;
        part[wid - 1][lane * 4 + 1] = acc1;
        part[wid - 1][lane * 4 + 2] = acc2;
        part[wid - 1][lane * 4 + 3] = acc3;
    }
    __syncthreads();
    if (wid == 0) {
        const float wd = dinv[d];
        acc0 += part[0][lane*4+0] + part[1][lane*4+0] + part[2][lane*4+0];
        acc1 += part[0][lane*4+1] + part[1][lane*4+1] + part[2][lane*4+1];
        acc2 += part[0][lane*4+2] + part[1][lane*4+2] + part[2][lane*4+2];
        acc3 += part[0][lane*4+3] + part[1][lane*4+3] + part[2][lane*4+3];
        union { unsigned short u[4]; uint2 v; } pk;
        pk.u[0] = f2bf(fmaxf(wd * acc0, 0.f));
        pk.u[1] = f2bf(fmaxf(wd * acc1, 0.f));
        pk.u[2] = f2bf(fmaxf(wd * acc2, 0.f));
        pk.u[3] = f2bf(fmaxf(wd * acc3, 0.f));
        *(uint2*)(out + (size_t)d * 256 + lane * 4) = pk.v;
    }
}

// F=64, hs bf16 in / fp32 out.
__global__ __launch_bounds__(256) void aggregate64_kernel(
        const unsigned short* __restrict__ hs, const int* __restrict__ rowptr,
        const int* __restrict__ csr, const float* __restrict__ dinv,
        float* __restrict__ out, int n) {
    const int d = blockIdx.x;
    const int tid = threadIdx.x;
    const int wid = tid >> 6;
    const int lane = tid & 63;
    const int beg = rowptr[d];
    const int end = rowptr[d + 1];

    float acc = 0.f;
    if (wid == 0) acc = bf2f(hs[(size_t)d * 64 + lane]);   // self-loop

    __shared__ unsigned int soff[256];
    const char* hb = (const char*)hs;
    for (int k0 = beg; k0 < end; k0 += 256) {
        int cnt = min(256, end - k0);
        if (tid < cnt) soff[tid] = (unsigned)csr[k0 + tid] * 128u;
        __syncthreads();
        #pragma unroll 8
        for (int e = wid; e < cnt; e += 4) {
            unsigned short t = *(const unsigned short*)(hb + soff[e] + lane * 2);
            acc += bf2f(t);
        }
        __syncthreads();
    }

    __shared__ float part[3][64];
    if (wid > 0) part[wid - 1][lane] = acc;
    __syncthreads();
    if (wid == 0) {
        acc += part[0][lane] + part[1][lane] + part[2][lane];
        out[(size_t)d * 64 + lane] = fmaxf(dinv[d] * acc, 0.f);
    }
}

// ---------------------------------------------------------------------------

static inline size_t align256(size_t v) { return (v + 255) & ~(size_t)255; }

extern "C" void kernel_launch(void* const* d_in, const int* in_sizes, int n_in,
                              void* d_out, int out_size, void* d_ws, size_t ws_size,
                              hipStream_t stream) {
    const float* x  = (const float*)d_in[0];
    const int*   ei = (const int*)d_in[1];
    const float* W1 = (const float*)d_in[2];
    const float* W3 = (const float*)d_in[3];

    const int n = in_sizes[0] / 256;     // 50000
    const int E = in_sizes[1] / 2;       // 1600000
    const int NB = (n + 63) >> 6;        // 782 buckets
    const int* src = ei;
    const int* dst = ei + E;

    char* w = (char*)d_ws;
    auto alloc = [&](size_t bytes) { char* p = w; w += align256(bytes); return p; };
    unsigned short* hs1  = (unsigned short*)alloc((size_t)n * 256 * 2);
    unsigned short* a1   = (unsigned short*)alloc((size_t)n * 256 * 2);
    unsigned short* hs2  = (unsigned short*)alloc((size_t)n * 64 * 2);
    unsigned short* W1t  = (unsigned short*)alloc(256 * 256 * 2);
    unsigned short* W3t  = (unsigned short*)alloc(64 * 256 * 2);
    float* dinv          = (float*)alloc((size_t)n * 4);
    int*   rowptr        = (int*)alloc((size_t)(n + 1) * 4);
    int*   csr           = (int*)alloc((size_t)E * 4);
    unsigned int* words  = (unsigned int*)alloc((size_t)E * 4);
    int*   blockhist     = (int*)alloc((size_t)NPART * NB * 4);
    int*   bbase         = (int*)alloc((size_t)NPART * NB * 4);
    int*   bofs          = (int*)alloc((size_t)(NB + 1) * 4);
    float* out           = (float*)d_out;

    wcvt2_kernel<<<(256 * 256 + 64 * 256 + 255) / 256, 256, 0, stream>>>(W1, W3, W1t, W3t);

    part_hist<<<NPART, 256, 0, stream>>>(dst, E, NB, blockhist);
    part_scan<<<1, 1024, 0, stream>>>(blockhist, bofs, bbase, NB);
    part_scatter<<<NPART, 256, 0, stream>>>(src, dst, bbase, words, E, NB);
    bucket_build<<<NB, 256, 0, stream>>>(words, bofs, rowptr, dinv, csr, n);

    // layer 1: hs1 = bf16((x @ W1)·dinv); a1 = relu-agg (bf16)
    {
        dim3 grid(1, (n + 127) / 128);
        mfma_gemm<256, 2, 2, true><<<grid, 256, 0, stream>>>(x, W1t, dinv, hs1, n, 256, 256);
        aggregate256_kernel<<<n, 256, 0, stream>>>(hs1, rowptr, csr, dinv, a1, n);
    }
    // layer 2: hs2 = bf16((a1 @ W3)·dinv); out = relu-agg (fp32)
    {
        dim3 grid(1, (n + 127) / 128);
        mfma_gemm<64, 4, 1, false><<<grid, 256, 0, stream>>>(a1, W3t, dinv, hs2, n, 64, 256);
        aggregate64_kernel<<<n, 256, 0, stream>>>(hs2, rowptr, csr, dinv, out, n);
    }
}